// Round 11
// baseline (756.467 us; speedup 1.0000x reference)
//
#include <hip/hip_runtime.h>

#define BIT 64
#define NCLASS 100
#define NTRAIN 100000
#define BATCH 512
// config scalars: MU=1, M=1, ETA=0.5, VUL=1, NTA=1

// ---- workspace element offsets (4-byte slots) ----
#define O_OWNER   0                          // int[100000]
#define O_LAB     200000                     // int[512]
#define O_UT      200512                     // float[64*512]
#define O_BSUM    233280                     // float[64*100]
#define O_COUNT   239680                     // float[100]
#define O_QSUM    239780                     // double (8B aligned)
#define O_MSUM    239782                     // double

typedef __attribute__((ext_vector_type(8))) short short8v;   // 8 bf16 = 4 VGPR
typedef __attribute__((ext_vector_type(4))) float f32x4;
typedef unsigned short ushortT;

__device__ __forceinline__ float signf(float x) {
    return (x > 0.f) ? 1.f : ((x < 0.f) ? -1.f : 0.f);
}

// one-instr bf16 pack: lo -> bits[15:0], hi -> bits[31:16]
__device__ __forceinline__ unsigned cvtpk(float lo, float hi) {
    unsigned r;
    asm("v_cvt_pk_bf16_f32 %0, %1, %2" : "=v"(r) : "v"(lo), "v"(hi));
    return r;
}
// quad_perm DPP lane exchanges (pure VALU, no LDS pipe)
__device__ __forceinline__ float dpp_x1(float x) {   // lane ^= 1
    union { float f; int i; } v; v.f = x;
    v.i = __builtin_amdgcn_mov_dpp(v.i, 0xB1, 0xF, 0xF, false);
    return v.f;
}
__device__ __forceinline__ float dpp_x2(float x) {   // lane ^= 2
    union { float f; int i; } v; v.f = x;
    v.i = __builtin_amdgcn_mov_dpp(v.i, 0x4E, 0xF, 0xF, false);
    return v.f;
}

// ---------------------------------------------------------------------------
// Fused prologue (k_prep + k_b + k_bsum): one block per bit-row r.
// Also writes uT[r][bb] = u[bb][r] for the metric's broadcast-load path.
// ---------------------------------------------------------------------------
__global__ __launch_bounds__(512) void k_pre(
        const float* __restrict__ y, const int* __restrict__ ind,
        const float* __restrict__ u, const float* __restrict__ V,
        int* owner, int* lab, float* Bsum, float* count, double* qsum,
        float* uT) {
    __shared__ float srow[BATCH];
    __shared__ int   labl[BATCH];
    __shared__ double wq[8];
    const int r = blockIdx.x;      // 0..63
    const int bb = threadIdx.x;    // 0..511

    const float* yrow = y + bb * NCLASS;
    int best = 0;
    for (int c = 0; c < NCLASS; ++c)
        if (yrow[c] > 0.5f) best = c;
    labl[bb] = best;
    if (r == 0) {
        lab[bb] = best;
        atomicMax(&owner[ind[bb]], bb);   // last-write-wins == max batch idx
    }

    const float v  = V[r * NCLASS + best];
    const float uu = u[bb * BIT + r];
    uT[r * BATCH + bb] = uu;              // coalesced transpose write
    const float bv = signf(signf(v) + uu);    // MU = 1
    srow[bb] = bv;
    const float d = bv - uu;
    double q = (double)(d * d);
    for (int off = 32; off; off >>= 1) q += __shfl_down(q, off);
    const int wid = bb >> 6, lane = bb & 63;
    if (lane == 0) wq[wid] = q;
    __syncthreads();                           // also covers srow/labl
    if (bb == 0) {
        double s = 0;
        for (int w = 0; w < 8; ++w) s += wq[w];
        atomicAdd(qsum, s);
    }

    if (bb < NCLASS) {
        float s = 0.f; int n = 0;
        for (int k = 0; k < BATCH; ++k) {      // broadcast LDS reads
            const bool hit = (labl[k] == bb);
            s += hit ? srow[k] : 0.f;
            n += hit;
        }
        Bsum[r * NCLASS + bb] = s;
        if (r == 0) count[bb] = (float)n;
    }
}

// ---------------------------------------------------------------------------
// GD body: the Round-6/10 best-measured structure, VERBATIM, isolated in its
// own __noinline__ function so metric edits can never perturb its codegen
// (rule #19). Own __shared__ arrays + 16KB touched pad -> block LDS > 81920
// -> 1 block/CU -> GD owns CU0's LDS pipe exclusively.
// ---------------------------------------------------------------------------
__device__ __noinline__ void gd_body(
        const float* __restrict__ V, const float* __restrict__ Bsum,
        const float* __restrict__ count, float* __restrict__ out) {
    __shared__ ushortT SAb[16384];    // 2 x 8192 shorts (32 KB)
    __shared__ ushortT SBb[14336];    // 2 x 7168 shorts (28 KB)
    __shared__ ushortT SMf[4096];     // 8 KB
    __shared__ float   rs[64];
    __shared__ float   xpad[4096];    // 16 KB exclusivity pad (touched once)

    const int t = threadIdx.x, l = t & 63, w = t >> 6;
    ((volatile float*)xpad)[t] = 0.f;     // keep pad allocated

    const int g = l >> 4, c16 = l & 15;
    const int h = w >> 2;           // 0..1
    const int mtile = w & 3;        // 0..3
    const int m = mtile * 16 + c16; // owned bit-row
    const bool dg = ((mtile >> 1) == h);   // rowsum duty (waves 0,1,6,7)
    const short8v ONES = {0x3F80,0x3F80,0x3F80,0x3F80,
                          0x3F80,0x3F80,0x3F80,0x3F80};

    for (int i = t; i < 16384; i += 512) SAb[i] = 0;
    for (int i = t; i < 14336; i += 512) SBb[i] = 0;

    const float ci = 2.0f / 32768.0f;   // intra: mean over 64*512
    const float ce = 4.0f / 10000.0f;   // inter (VUL=1): 4/100^2
    const float cq = 2.0f / 6400.0f;    // quant (NTA=1)
    const float ce64 = 64.0f * ce;

    // ---- ownership: thread owns (m, n0..n0+3) per q; nt = 4h + q ----
    bool live[4];
    int sbO[4];
    float vreg[4][4], Kc[4][4], ncib[4][4];
    #pragma unroll
    for (int q = 0; q < 4; ++q) {
        const int nt = 4 * h + q;
        const int n0 = nt * 16 + 4 * g;
        const bool wact = (nt < 7);
        live[q] = wact && (n0 < NCLASS);
        sbO[q] = ((nt * 2 + (mtile >> 1)) * 64 +
                  (16 * (c16 >> 2) + 4 * g + (c16 & 3))) * 8 + 4 * (mtile & 1);
        #pragma unroll
        for (int r = 0; r < 4; ++r) {
            float v = 0.f, bs = 0.f, cn = 0.f;
            if (live[q]) {
                const int n = n0 + r;
                v  = V[m * NCLASS + n];
                bs = Bsum[m * NCLASS + n];
                cn = count[n];
            }
            vreg[q][r] = v;
            Kc[q][r]   = ci * cn + cq - 128.f * ce;
            ncib[q][r] = -ci * bs;
        }
    }
    const int saO0 = (mtile * 4 + 2 * h) * 512 + l * 8;       // ks = 2h
    const int saO1 = saO0 + 512;                              // ks = 2h+1

    // store current vreg into buffers (SA pairs + SB quad-transpose)
    auto store_frags = [&](ushortT* SAn, ushortT* SBn) {
        uint4 wa;
        wa.x = cvtpk(vreg[0][0], vreg[0][1]);
        wa.y = cvtpk(vreg[0][2], vreg[0][3]);
        wa.z = cvtpk(vreg[1][0], vreg[1][1]);
        wa.w = cvtpk(vreg[1][2], vreg[1][3]);
        *(uint4*)&SAn[saO0] = wa;
        wa.x = cvtpk(vreg[2][0], vreg[2][1]);
        wa.y = cvtpk(vreg[2][2], vreg[2][3]);
        wa.z = cvtpk(vreg[3][0], vreg[3][1]);
        wa.w = cvtpk(vreg[3][2], vreg[3][3]);
        *(uint4*)&SAn[saO1] = wa;
        #pragma unroll
        for (int q = 0; q < 4; ++q) {
            if (4 * h + q < 7) {
                float a0 = vreg[q][0], a1 = vreg[q][1];
                float a2 = vreg[q][2], a3 = vreg[q][3];
                // 4x4 transpose across the aligned quad (DPP, no LDS)
                float t0 = dpp_x1(a1), t1 = dpp_x1(a0);
                float t2 = dpp_x1(a3), t3 = dpp_x1(a2);
                const bool o1 = (l & 1);
                float c0 = o1 ? t0 : a0;
                float c1 = o1 ? a1 : t1;
                float c2 = o1 ? t2 : a2;
                float c3 = o1 ? a3 : t3;
                float u0 = dpp_x2(c2), u1 = dpp_x2(c3);
                float u2 = dpp_x2(c0), u3 = dpp_x2(c1);
                const bool o2 = (l & 2);
                float d0 = o2 ? u0 : c0;
                float d1 = o2 ? u1 : c1;
                float d2 = o2 ? c2 : u2;
                float d3 = o2 ? c3 : u3;
                uint2 wb;
                wb.x = cvtpk(d0, d1);
                wb.y = cvtpk(d2, d3);
                *(uint2*)&SBn[sbO[q]] = wb;
            }
        }
    };

    __syncthreads();          // zeros visible
    store_frags(SAb, SBb);    // fill buffer 0
    __syncthreads();

    int cur = 0;
    for (int step = 0; step < 200; ++step) {
        float alpha = 0.03f;
        if (step >= 149) alpha *= 0.1f;
        if (step >= 179) alpha *= 0.1f;

        const ushortT* SAc = SAb + cur * 8192;

        // ---- M = V V^T: vertical pair (2h, mtile), (2h+1, mtile) ----
        f32x4 aM0 = {0.f,0.f,0.f,0.f}, aM1 = {0.f,0.f,0.f,0.f};
        f32x4 aR  = {0.f,0.f,0.f,0.f};
        #pragma unroll
        for (int ks = 0; ks < 4; ++ks) {
            short8v b  = *(const short8v*)&SAc[mtile * 2048 + ks * 512 + l * 8];
            short8v a0 = *(const short8v*)&SAc[(2 * h) * 2048 + ks * 512 + l * 8];
            short8v a1 = *(const short8v*)&SAc[(2 * h + 1) * 2048 + ks * 512 + l * 8];
            aM0 = __builtin_amdgcn_mfma_f32_16x16x32_bf16(a0, b, aM0, 0, 0, 0);
            aM1 = __builtin_amdgcn_mfma_f32_16x16x32_bf16(a1, b, aM1, 0, 0, 0);
            if (dg)
                aR = __builtin_amdgcn_mfma_f32_16x16x32_bf16(b, ONES, aR, 0, 0, 0);
        }
        {   // one conflict-free b128 into SM panel (mtile, h)
            uint4 sm;
            sm.x = cvtpk(aM0[0], aM0[1]);
            sm.y = cvtpk(aM0[2], aM0[3]);
            sm.z = cvtpk(aM1[0], aM1[1]);
            sm.w = cvtpk(aM1[2], aM1[3]);
            *(uint4*)&SMf[(mtile * 2 + h) * 512 + l * 8] = sm;
        }
        if (dg && c16 == 0)
            *(f32x4*)&rs[mtile * 16 + 4 * g] = aR;
        __syncthreads();

        // ---- P^T = V^T M : q-slots nt = 4h+q, shared B = SM[mtile] ----
        const ushortT* SBc = SBb + cur * 7168;
        f32x4 p[4];
        #pragma unroll
        for (int q = 0; q < 4; ++q) p[q] = (f32x4){0.f,0.f,0.f,0.f};
        #pragma unroll
        for (int kb = 0; kb < 2; ++kb) {
            short8v bP = *(const short8v*)&SMf[(mtile * 2 + kb) * 512 + l * 8];
            #pragma unroll
            for (int q = 0; q < 4; ++q) {
                if (4 * h + q < 7) {
                    short8v aP = *(const short8v*)
                        &SBc[((4 * h + q) * 2 + kb) * 512 + l * 8];
                    p[q] = __builtin_amdgcn_mfma_f32_16x16x32_bf16(aP, bP, p[q], 0, 0, 0);
                }
            }
        }
        const float rsm = rs[m];

        // ---- update own elements, store into NEXT buffers ----
        #pragma unroll
        for (int q = 0; q < 4; ++q) {
            if (4 * h + q < 7) {
                #pragma unroll
                for (int r = 0; r < 4; ++r) {
                    const float v = vreg[q][r];
                    float t1 = __builtin_fmaf(Kc[q][r], v, ncib[q][r]);
                    t1 = __builtin_fmaf(ce,   p[q][r], t1);
                    t1 = __builtin_fmaf(ce64, rsm,     t1);
                    t1 -= __builtin_copysignf(cq, v);
                    float vn = __builtin_fmaf(-alpha, t1, v);
                    vreg[q][r] = live[q] ? vn : 0.f;
                }
            }
        }
        store_frags(SAb + (cur ^ 1) * 8192, SBb + (cur ^ 1) * 7168);
        __syncthreads();
        cur ^= 1;
    }

    // write V_new from f32 register master copy
    #pragma unroll
    for (int q = 0; q < 4; ++q) {
        if (live[q]) {
            const int n0 = (4 * h + q) * 16 + 4 * g;
            #pragma unroll
            for (int r = 0; r < 4; ++r)
                out[1 + m * NCLASS + n0 + r] = vreg[q][r];
        }
    }
}

// ---------------------------------------------------------------------------
// Metric body: Round-9 global-broadcast-uT path VERBATIM (measured ~165 us,
// off the LDS pipe), isolated in its own __noinline__ function.
// ---------------------------------------------------------------------------
__device__ __noinline__ void metric_body(
        const float* __restrict__ u, const float* __restrict__ U,
        const float* __restrict__ Y, const int* __restrict__ lab,
        const int* __restrict__ owner, const float* __restrict__ uT,
        double* msum) {
    __shared__ double wsumM[8];
    __shared__ int    tlsM[256];

    const int t = threadIdx.x;
    const int jj = t & 255;
    const int j = (blockIdx.x - 1) * 256 + jj;
    const int half = t >> 8;
    const bool jok = (j < NTRAIN);

    // local tlab slice from one-hot Y, patched by the scatter
    if (half == 0) {
        int tl = 0;
        if (jok) {
            for (int c = 0; c < NCLASS; ++c)
                if (Y[(size_t)c * NTRAIN + j] > 0.5f) tl = c;
            int ow = owner[j];
            if (ow >= 0) tl = lab[ow];
        }
        tlsM[jj] = tl;
    }
    __syncthreads();
    const int tl = tlsM[jj];

    const float* colbase = U;
    size_t cstride = NTRAIN;
    if (jok) {
        int ow = owner[j];
        if (ow >= 0) { colbase = u + (size_t)ow * BIT; cstride = 1; }
        else         { colbase = U + j; }
    }

    float lsum = 0.f;
    for (int ch = 0; ch < 4; ++ch) {
        // wave-uniform batch-row base -> broadcast loads of uT / lab
        const int b0u = __builtin_amdgcn_readfirstlane((half * 4 + ch) * 64);

        if (jok) {
            float acc[64];
            #pragma unroll
            for (int k = 0; k < 64; ++k) acc[k] = 0.f;
            #pragma unroll 4
            for (int r = 0; r < BIT; ++r) {
                float Uv = colbase[(size_t)r * cstride];   // vector load
                const float* urow = &uT[r * BATCH + b0u];  // uniform addr
                #pragma unroll
                for (int qq = 0; qq < 16; ++qq) {
                    float4 uv = *(const float4*)&urow[qq * 4];  // broadcast
                    acc[4 * qq + 0] += uv.x * Uv;
                    acc[4 * qq + 1] += uv.y * Uv;
                    acc[4 * qq + 2] += uv.z * Uv;
                    acc[4 * qq + 3] += uv.w * Uv;
                }
            }
            #pragma unroll
            for (int k = 0; k < 64; ++k) {
                const int lv = lab[b0u + k];               // broadcast
                float ip = fminf(fmaxf(0.5f * acc[k], -100.f), 50.f);
                float x = (lv == tl) ? (1.0f - ip) : (1.0f + ip);   // M=1
                lsum += fmaxf(x, 0.f) + __logf(1.f + __expf(-fabsf(x)));
            }
        }
    }

    double d = (double)lsum;
    for (int off = 32; off; off >>= 1) d += __shfl_down(d, off);
    const int wid = t >> 6, lane = t & 63;
    if (lane == 0) wsumM[wid] = d;
    __syncthreads();
    if (t == 0) {
        double s = 0;
        for (int ww = 0; ww < 8; ++ww) s += wsumM[ww];
        atomicAdd(msum, s);
    }
}

// ---------------------------------------------------------------------------
// FUSED kernel: block 0 = GD (exclusive CU via >81920B LDS, 1 block/CU);
// blocks 1..391 = metric. Thin dispatcher; each branch's codegen is frozen
// inside its own __noinline__ function.
// ---------------------------------------------------------------------------
__global__ __launch_bounds__(512, 2) void k_main(
        const float* __restrict__ V, const float* __restrict__ Bsum,
        const float* __restrict__ count, const float* __restrict__ u,
        const float* __restrict__ U, const float* __restrict__ Y,
        const int* __restrict__ lab, const int* __restrict__ owner,
        const float* __restrict__ uT, double* msum, float* __restrict__ out) {
    if (blockIdx.x == 0) {
        gd_body(V, Bsum, count, out);
    } else {
        metric_body(u, U, Y, lab, owner, uT, msum);
    }
}

__global__ void k_final(const double* __restrict__ msum,
                        const double* __restrict__ qsum, float* out) {
    if (threadIdx.x == 0) {
        double loss = (*msum) / ((double)BATCH * (double)NTRAIN)
                    + 0.5 * ((*qsum) / ((double)BIT * (double)BATCH));
        out[0] = (float)loss;
    }
}

extern "C" void kernel_launch(void* const* d_in, const int* in_sizes, int n_in,
                              void* d_out, int out_size, void* d_ws, size_t ws_size,
                              hipStream_t stream) {
    const float* u   = (const float*)d_in[0];
    const float* y   = (const float*)d_in[1];
    const int*   ind = (const int*)d_in[2];
    const float* U   = (const float*)d_in[3];
    const float* Y   = (const float*)d_in[4];
    const float* V   = (const float*)d_in[5];
    float* out = (float*)d_out;

    int*   wsI = (int*)d_ws;
    float* wsF = (float*)d_ws;
    int*   owner = wsI + O_OWNER;
    int*   lab   = wsI + O_LAB;
    float* uT    = wsF + O_UT;
    float* Bsum  = wsF + O_BSUM;
    float* count = wsF + O_COUNT;
    double* qsum = (double*)(wsF + O_QSUM);
    double* msum = (double*)(wsF + O_MSUM);

    hipMemsetAsync(owner, 0xFF, NTRAIN * sizeof(int), stream);        // -1
    hipMemsetAsync(wsF + O_QSUM, 0, 4 * sizeof(float), stream);       // qsum,msum

    k_pre<<<64, 512, 0, stream>>>(y, ind, u, V, owner, lab, Bsum, count, qsum, uT);
    k_main<<<1 + (NTRAIN + 255) / 256, 512, 0, stream>>>(
        V, Bsum, count, u, U, Y, lab, owner, uT, msum, out);
    k_final<<<1, 64, 0, stream>>>(msum, qsum, out);
}

// Round 12
// 364.456 us; speedup vs baseline: 2.0756x; 2.0756x over previous
//
#include <hip/hip_runtime.h>

#define BIT 64
#define NCLASS 100
#define NTRAIN 100000
#define BATCH 512
// config scalars: MU=1, M=1, ETA=0.5, VUL=1, NTA=1

// ---- workspace element offsets (4-byte slots) ----
#define O_OWNER   0                          // int[100000]
#define O_LAB     200000                     // int[512]
#define O_BSUM    233280                     // float[64*100]
#define O_COUNT   239680                     // float[100]
#define O_QSUM    239780                     // double (8B aligned)
#define O_MSUM    239782                     // double

typedef __attribute__((ext_vector_type(8))) short short8v;   // 8 bf16 = 4 VGPR
typedef __attribute__((ext_vector_type(4))) float f32x4;
typedef unsigned short ushortT;

__device__ __forceinline__ float signf(float x) {
    return (x > 0.f) ? 1.f : ((x < 0.f) ? -1.f : 0.f);
}

// one-instr bf16 pack: lo -> bits[15:0], hi -> bits[31:16]
__device__ __forceinline__ unsigned cvtpk(float lo, float hi) {
    unsigned r;
    asm("v_cvt_pk_bf16_f32 %0, %1, %2" : "=v"(r) : "v"(lo), "v"(hi));
    return r;
}
// quad_perm DPP lane exchanges (pure VALU, no LDS pipe)
__device__ __forceinline__ float dpp_x1(float x) {   // lane ^= 1
    union { float f; int i; } v; v.f = x;
    v.i = __builtin_amdgcn_mov_dpp(v.i, 0xB1, 0xF, 0xF, false);
    return v.f;
}
__device__ __forceinline__ float dpp_x2(float x) {   // lane ^= 2
    union { float f; int i; } v; v.f = x;
    v.i = __builtin_amdgcn_mov_dpp(v.i, 0x4E, 0xF, 0xF, false);
    return v.f;
}

// ---------------------------------------------------------------------------
// Fused prologue (k_prep + k_b + k_bsum): one block per bit-row r.
// Separate __global__ function -> cannot perturb k_main's codegen (rule #19:
// only same-function branches share regalloc context).
// ---------------------------------------------------------------------------
__global__ __launch_bounds__(512) void k_pre(
        const float* __restrict__ y, const int* __restrict__ ind,
        const float* __restrict__ u, const float* __restrict__ V,
        int* owner, int* lab, float* Bsum, float* count, double* qsum) {
    __shared__ float srow[BATCH];
    __shared__ int   labl[BATCH];
    __shared__ double wq[8];
    const int r = blockIdx.x;      // 0..63
    const int bb = threadIdx.x;    // 0..511

    const float* yrow = y + bb * NCLASS;
    int best = 0;
    for (int c = 0; c < NCLASS; ++c)
        if (yrow[c] > 0.5f) best = c;
    labl[bb] = best;
    if (r == 0) {
        lab[bb] = best;
        atomicMax(&owner[ind[bb]], bb);   // last-write-wins == max batch idx
    }

    const float v  = V[r * NCLASS + best];
    const float uu = u[bb * BIT + r];
    const float bv = signf(signf(v) + uu);    // MU = 1
    srow[bb] = bv;
    const float d = bv - uu;
    double q = (double)(d * d);
    for (int off = 32; off; off >>= 1) q += __shfl_down(q, off);
    const int wid = bb >> 6, lane = bb & 63;
    if (lane == 0) wq[wid] = q;
    __syncthreads();                           // also covers srow/labl
    if (bb == 0) {
        double s = 0;
        for (int w = 0; w < 8; ++w) s += wq[w];
        atomicAdd(qsum, s);
    }

    if (bb < NCLASS) {
        float s = 0.f; int n = 0;
        for (int k = 0; k < BATCH; ++k) {      // broadcast LDS reads
            const bool hit = (labl[k] == bb);
            s += hit ? srow[k] : 0.f;
            n += hit;
        }
        Bsum[r * NCLASS + bb] = s;
        if (r == 0) count[bb] = (float)n;
    }
}

// ---------------------------------------------------------------------------
// FUSED kernel: block 0 = 200-step GD on V (1 CU); blocks 1..391 = metric
// (which also computes its own tlab slice from Y).
// BYTE-IDENTICAL to the Round-6 best-measured build (344 us, VGPR 56):
//   M-phase : wave (h = w>>2, mtile = w&3) computes the VERTICAL tile pair
//             (2h, mtile), (2h+1, mtile) sharing B = SA[mtile]; one
//             conflict-free b128 SM write per wave.
//             Rowsum via ones-MFMA on waves with mtile>>1 == h.
//   P-phase : P^T = V^T * M; thread owns (1 m, 4 n) per q-slot, nt = 4h+q.
//   SB      : in-register 4x4 quad transpose (2 DPP quad_perm stages).
// ---------------------------------------------------------------------------
__global__ __launch_bounds__(512, 4) void k_main(
        const float* __restrict__ V, const float* __restrict__ Bsum,
        const float* __restrict__ count, const float* __restrict__ u,
        const float* __restrict__ U, const float* __restrict__ Y,
        const int* __restrict__ lab, const int* __restrict__ owner,
        double* msum, float* __restrict__ out) {
    __shared__ __align__(16) char smem[69888];

    if (blockIdx.x == 0) {
        // ================= GD =================
        ushortT* SAb = (ushortT*)smem;              // 2 x 8192 shorts (32 KB)
        ushortT* SBb = (ushortT*)(smem + 32768);    // 2 x 7168 shorts (28 KB)
        ushortT* SMf = (ushortT*)(smem + 61440);    // 4096 shorts (8 KB)
        float*   rs  = (float*)(smem + 69632);      // 64 floats

        const int t = threadIdx.x, l = t & 63, w = t >> 6;
        const int g = l >> 4, c16 = l & 15;
        const int h = w >> 2;           // 0..1
        const int mtile = w & 3;        // 0..3
        const int m = mtile * 16 + c16; // owned bit-row
        const bool dg = ((mtile >> 1) == h);   // rowsum duty (waves 0,1,6,7)
        const short8v ONES = {0x3F80,0x3F80,0x3F80,0x3F80,
                              0x3F80,0x3F80,0x3F80,0x3F80};

        for (int i = t; i < 16384; i += 512) SAb[i] = 0;
        for (int i = t; i < 14336; i += 512) SBb[i] = 0;

        const float ci = 2.0f / 32768.0f;   // intra: mean over 64*512
        const float ce = 4.0f / 10000.0f;   // inter (VUL=1): 4/100^2
        const float cq = 2.0f / 6400.0f;    // quant (NTA=1)
        const float ce64 = 64.0f * ce;

        // ---- ownership: thread owns (m, n0..n0+3) per q; nt = 4h + q ----
        bool live[4];
        int sbO[4];
        float vreg[4][4], Kc[4][4], ncib[4][4];
        #pragma unroll
        for (int q = 0; q < 4; ++q) {
            const int nt = 4 * h + q;
            const int n0 = nt * 16 + 4 * g;
            const bool wact = (nt < 7);
            live[q] = wact && (n0 < NCLASS);
            // SB (transposed column) target: x = 16*(c16>>2) + (n&15)
            sbO[q] = ((nt * 2 + (mtile >> 1)) * 64 +
                      (16 * (c16 >> 2) + 4 * g + (c16 & 3))) * 8 + 4 * (mtile & 1);
            #pragma unroll
            for (int r = 0; r < 4; ++r) {
                float v = 0.f, bs = 0.f, cn = 0.f;
                if (live[q]) {
                    const int n = n0 + r;
                    v  = V[m * NCLASS + n];
                    bs = Bsum[m * NCLASS + n];
                    cn = count[n];
                }
                vreg[q][r] = v;
                Kc[q][r]   = ci * cn + cq - 128.f * ce;
                ncib[q][r] = -ci * bs;
            }
        }
        const int saO0 = (mtile * 4 + 2 * h) * 512 + l * 8;       // ks = 2h
        const int saO1 = saO0 + 512;                              // ks = 2h+1

        // store current vreg into buffers (SA pairs + SB quad-transpose)
        auto store_frags = [&](ushortT* SAn, ushortT* SBn) {
            uint4 wa;
            wa.x = cvtpk(vreg[0][0], vreg[0][1]);
            wa.y = cvtpk(vreg[0][2], vreg[0][3]);
            wa.z = cvtpk(vreg[1][0], vreg[1][1]);
            wa.w = cvtpk(vreg[1][2], vreg[1][3]);
            *(uint4*)&SAn[saO0] = wa;
            wa.x = cvtpk(vreg[2][0], vreg[2][1]);
            wa.y = cvtpk(vreg[2][2], vreg[2][3]);
            wa.z = cvtpk(vreg[3][0], vreg[3][1]);
            wa.w = cvtpk(vreg[3][2], vreg[3][3]);
            *(uint4*)&SAn[saO1] = wa;
            #pragma unroll
            for (int q = 0; q < 4; ++q) {
                if (4 * h + q < 7) {
                    float a0 = vreg[q][0], a1 = vreg[q][1];
                    float a2 = vreg[q][2], a3 = vreg[q][3];
                    // 4x4 transpose across the aligned quad (DPP, no LDS)
                    float t0 = dpp_x1(a1), t1 = dpp_x1(a0);
                    float t2 = dpp_x1(a3), t3 = dpp_x1(a2);
                    const bool o1 = (l & 1);
                    float c0 = o1 ? t0 : a0;
                    float c1 = o1 ? a1 : t1;
                    float c2 = o1 ? t2 : a2;
                    float c3 = o1 ? a3 : t3;
                    float u0 = dpp_x2(c2), u1 = dpp_x2(c3);
                    float u2 = dpp_x2(c0), u3 = dpp_x2(c1);
                    const bool o2 = (l & 2);
                    float d0 = o2 ? u0 : c0;
                    float d1 = o2 ? u1 : c1;
                    float d2 = o2 ? c2 : u2;
                    float d3 = o2 ? c3 : u3;
                    uint2 wb;
                    wb.x = cvtpk(d0, d1);
                    wb.y = cvtpk(d2, d3);
                    *(uint2*)&SBn[sbO[q]] = wb;
                }
            }
        };

        __syncthreads();          // zeros visible
        store_frags(SAb, SBb);    // fill buffer 0
        __syncthreads();

        int cur = 0;
        for (int step = 0; step < 200; ++step) {
            float alpha = 0.03f;
            if (step >= 149) alpha *= 0.1f;
            if (step >= 179) alpha *= 0.1f;

            const ushortT* SAc = SAb + cur * 8192;

            // ---- M = V V^T: vertical pair (2h, mtile), (2h+1, mtile) ----
            f32x4 aM0 = {0.f,0.f,0.f,0.f}, aM1 = {0.f,0.f,0.f,0.f};
            f32x4 aR  = {0.f,0.f,0.f,0.f};
            #pragma unroll
            for (int ks = 0; ks < 4; ++ks) {
                short8v b  = *(const short8v*)&SAc[mtile * 2048 + ks * 512 + l * 8];
                short8v a0 = *(const short8v*)&SAc[(2 * h) * 2048 + ks * 512 + l * 8];
                short8v a1 = *(const short8v*)&SAc[(2 * h + 1) * 2048 + ks * 512 + l * 8];
                aM0 = __builtin_amdgcn_mfma_f32_16x16x32_bf16(a0, b, aM0, 0, 0, 0);
                aM1 = __builtin_amdgcn_mfma_f32_16x16x32_bf16(a1, b, aM1, 0, 0, 0);
                if (dg)
                    aR = __builtin_amdgcn_mfma_f32_16x16x32_bf16(b, ONES, aR, 0, 0, 0);
            }
            {   // one conflict-free b128 into SM panel (mtile, h)
                uint4 sm;
                sm.x = cvtpk(aM0[0], aM0[1]);
                sm.y = cvtpk(aM0[2], aM0[3]);
                sm.z = cvtpk(aM1[0], aM1[1]);
                sm.w = cvtpk(aM1[2], aM1[3]);
                *(uint4*)&SMf[(mtile * 2 + h) * 512 + l * 8] = sm;
            }
            if (dg && c16 == 0)
                *(f32x4*)&rs[mtile * 16 + 4 * g] = aR;
            __syncthreads();

            // ---- P^T = V^T M : q-slots nt = 4h+q, shared B = SM[mtile] ----
            const ushortT* SBc = SBb + cur * 7168;
            f32x4 p[4];
            #pragma unroll
            for (int q = 0; q < 4; ++q) p[q] = (f32x4){0.f,0.f,0.f,0.f};
            #pragma unroll
            for (int kb = 0; kb < 2; ++kb) {
                short8v bP = *(const short8v*)&SMf[(mtile * 2 + kb) * 512 + l * 8];
                #pragma unroll
                for (int q = 0; q < 4; ++q) {
                    if (4 * h + q < 7) {
                        short8v aP = *(const short8v*)
                            &SBc[((4 * h + q) * 2 + kb) * 512 + l * 8];
                        p[q] = __builtin_amdgcn_mfma_f32_16x16x32_bf16(aP, bP, p[q], 0, 0, 0);
                    }
                }
            }
            const float rsm = rs[m];

            // ---- update own elements, store into NEXT buffers ----
            #pragma unroll
            for (int q = 0; q < 4; ++q) {
                if (4 * h + q < 7) {
                    #pragma unroll
                    for (int r = 0; r < 4; ++r) {
                        const float v = vreg[q][r];
                        float t1 = __builtin_fmaf(Kc[q][r], v, ncib[q][r]);
                        t1 = __builtin_fmaf(ce,   p[q][r], t1);
                        t1 = __builtin_fmaf(ce64, rsm,     t1);
                        t1 -= __builtin_copysignf(cq, v);
                        float vn = __builtin_fmaf(-alpha, t1, v);
                        vreg[q][r] = live[q] ? vn : 0.f;
                    }
                }
            }
            store_frags(SAb + (cur ^ 1) * 8192, SBb + (cur ^ 1) * 7168);
            __syncthreads();
            cur ^= 1;
        }

        // write V_new from f32 register master copy
        #pragma unroll
        for (int q = 0; q < 4; ++q) {
            if (live[q]) {
                const int n0 = (4 * h + q) * 16 + 4 * g;
                #pragma unroll
                for (int r = 0; r < 4; ++r)
                    out[1 + m * NCLASS + n0 + r] = vreg[q][r];
            }
        }
    } else {
        // ================= metric =================
        float*  ut   = (float*)smem;                // [2][64*68]
        int*    slab = (int*)(smem + 34816);        // [512]
        double* wsum = (double*)(smem + 36864);     // [8]
        int*    tls  = (int*)(smem + 36928);        // [256]

        const int t = threadIdx.x;
        const int jj = t & 255;
        const int j = (blockIdx.x - 1) * 256 + jj;
        const int half = t >> 8;
        const bool jok = (j < NTRAIN);
        slab[t] = lab[t];

        // local tlab slice from one-hot Y, patched by the scatter
        if (half == 0) {
            int tl = 0;
            if (jok) {
                for (int c = 0; c < NCLASS; ++c)
                    if (Y[(size_t)c * NTRAIN + j] > 0.5f) tl = c;
                int ow = owner[j];
                if (ow >= 0) tl = lab[ow];
            }
            tls[jj] = tl;
        }
        __syncthreads();
        const int tl = tls[jj];

        const float* colbase = U;
        size_t cstride = NTRAIN;
        if (jok) {
            int ow = owner[j];
            if (ow >= 0) { colbase = u + (size_t)ow * BIT; cstride = 1; }
            else         { colbase = U + j; }
        }

        float lsum = 0.f;
        for (int ch = 0; ch < 4; ++ch) {
            __syncthreads();   // previous chunk's readers done
            for (int i = t; i < 8192; i += 512) {
                int buf = i >> 12, k = (i >> 6) & 63, r = i & 63;
                ut[buf * 4352 + r * 68 + k] = u[((buf * 4 + ch) * 64 + k) * BIT + r];
            }
            __syncthreads();

            if (jok) {
                const float* myut = ut + half * 4352;
                float acc[64];
                #pragma unroll
                for (int k = 0; k < 64; ++k) acc[k] = 0.f;
                #pragma unroll 2
                for (int r = 0; r < BIT; ++r) {
                    float Uv = colbase[(size_t)r * cstride];
                    const float* urow = &myut[r * 68];
                    #pragma unroll
                    for (int qq = 0; qq < 16; ++qq) {
                        float4 uv = *(const float4*)&urow[qq * 4];
                        acc[4 * qq + 0] += uv.x * Uv;
                        acc[4 * qq + 1] += uv.y * Uv;
                        acc[4 * qq + 2] += uv.z * Uv;
                        acc[4 * qq + 3] += uv.w * Uv;
                    }
                }
                const int b0 = (half * 4 + ch) * 64;
                #pragma unroll
                for (int k = 0; k < 64; ++k) {
                    float ip = fminf(fmaxf(0.5f * acc[k], -100.f), 50.f);
                    float x = (slab[b0 + k] == tl) ? (1.0f - ip) : (1.0f + ip); // M=1
                    lsum += fmaxf(x, 0.f) + __logf(1.f + __expf(-fabsf(x)));
                }
            }
        }

        double d = (double)lsum;
        for (int off = 32; off; off >>= 1) d += __shfl_down(d, off);
        const int wid = t >> 6, lane = t & 63;
        if (lane == 0) wsum[wid] = d;
        __syncthreads();
        if (t == 0) {
            double s = 0;
            for (int ww = 0; ww < 8; ++ww) s += wsum[ww];
            atomicAdd(msum, s);
        }
    }
}

__global__ void k_final(const double* __restrict__ msum,
                        const double* __restrict__ qsum, float* out) {
    if (threadIdx.x == 0) {
        double loss = (*msum) / ((double)BATCH * (double)NTRAIN)
                    + 0.5 * ((*qsum) / ((double)BIT * (double)BATCH));
        out[0] = (float)loss;
    }
}

extern "C" void kernel_launch(void* const* d_in, const int* in_sizes, int n_in,
                              void* d_out, int out_size, void* d_ws, size_t ws_size,
                              hipStream_t stream) {
    const float* u   = (const float*)d_in[0];
    const float* y   = (const float*)d_in[1];
    const int*   ind = (const int*)d_in[2];
    const float* U   = (const float*)d_in[3];
    const float* Y   = (const float*)d_in[4];
    const float* V   = (const float*)d_in[5];
    float* out = (float*)d_out;

    int*   wsI = (int*)d_ws;
    float* wsF = (float*)d_ws;
    int*   owner = wsI + O_OWNER;
    int*   lab   = wsI + O_LAB;
    float* Bsum  = wsF + O_BSUM;
    float* count = wsF + O_COUNT;
    double* qsum = (double*)(wsF + O_QSUM);
    double* msum = (double*)(wsF + O_MSUM);

    hipMemsetAsync(owner, 0xFF, NTRAIN * sizeof(int), stream);        // -1
    hipMemsetAsync(wsF + O_QSUM, 0, 4 * sizeof(float), stream);       // qsum,msum

    k_pre<<<64, 512, 0, stream>>>(y, ind, u, V, owner, lab, Bsum, count, qsum);
    k_main<<<1 + (NTRAIN + 255) / 256, 512, 0, stream>>>(
        V, Bsum, count, u, U, Y, lab, owner, msum, out);
    k_final<<<1, 64, 0, stream>>>(msum, qsum, out);
}